// Round 2
// baseline (542.698 us; speedup 1.0000x reference)
//
#include <hip/hip_runtime.h>
#include <hip/hip_bf16.h>
#include <math.h>

// Fused LabelSmoothingCrossEntropy + Focal + SuperLoss(LambertW) over
// [B=2048, C=50257] fp32 logits. Memory-bound: one pass over 412 MB.
//
// R4: attack row_kernel's BW gap (est. ~1.65 TB/s vs 6.3 achievable):
//  - plain (cached) loads instead of nontemporal: L2 line handling on the
//    read path; streaming single-pass so pollution is irrelevant.
//  - manual 1-deep software pipeline: next iteration's 2x vf4 loaded into
//    regs before consuming current -> 4 KB in flight per wave regardless
//    of compiler waitcnt placement.
//  - wave-uniform rare-rescale branch: __any(mx > m) is almost never true
//    for N(0,1) data after the first few KB; fast path = 4 exps + adds,
//    no loop-carried rescale mul. Bit-identical (skipped rescale is *1.0).
//  - __launch_bounds__(256, 8): pin 64-VGPR budget -> 8 blocks/CU resident.
// mid_kernel / final_kernel unchanged (R3-verified).

#define EPS_LS 0.01
#define LAM 0.5
#define ALPHA 0.25

typedef float vf4 __attribute__((ext_vector_type(4)));

struct Acc { float m, s, sx; };

__device__ __forceinline__ void acc_vec(Acc& a, vf4 v) {
    float mx = fmaxf(fmaxf(v.x, v.y), fmaxf(v.z, v.w));
    if (__builtin_expect(__any(mx > a.m), 0)) {
        // slow path: some lane updates its max. Lanes with mx<=m compute
        // s*expf(0)=s exactly, so this is bit-identical to unconditional.
        float nm = fmaxf(a.m, mx);
        a.s = a.s * __expf(a.m - nm)
            + __expf(v.x - nm) + __expf(v.y - nm)
            + __expf(v.z - nm) + __expf(v.w - nm);
        a.m = nm;
    } else {
        a.s += __expf(v.x - a.m) + __expf(v.y - a.m)
             + __expf(v.z - a.m) + __expf(v.w - a.m);
    }
    a.sx += (v.x + v.y) + (v.z + v.w);
}

__device__ __forceinline__ void acc_merge(Acc& a, float mo, float so, float sxo) {
    float nm = fmaxf(a.m, mo);
    a.s = a.s * __expf(a.m - nm) + so * __expf(mo - nm);
    a.m = nm;
    a.sx += sxo;
}

__global__ __launch_bounds__(256, 8) void
row_kernel(const float* __restrict__ x, float4* __restrict__ ws, int C) {
    const int row = blockIdx.x;
    const int tid = threadIdx.x;
    const float* xr = x + (size_t)row * (size_t)C;

    Acc a0 = { -3.402823466e38f, 0.0f, 0.0f };
    Acc a1 = { -3.402823466e38f, 0.0f, 0.0f };

    // peel to 16B alignment (rows start at row*C, C%4==1 -> rotates)
    const int mis = (int)(((size_t)row * (size_t)C) & 3);
    const int pre = (4 - mis) & 3;
    if (tid < pre) {
        float v = xr[tid];
        a0.m = v; a0.s = 1.0f; a0.sx = v;
    }
    const int nvec = (C - pre) >> 2;
    const vf4* xv = reinterpret_cast<const vf4*>(xr + pre);

    // software-pipelined main loop: consume (i, i+256), prefetch (i+512, i+768)
    int i = tid;
    if (i + 256 < nvec) {
        vf4 n0 = xv[i];
        vf4 n1 = xv[i + 256];
        for (;;) {
            const int j = i + 512;
            vf4 v0 = n0, v1 = n1;
            const bool more = (j + 256 < nvec);
            if (more) { n0 = xv[j]; n1 = xv[j + 256]; }
            acc_vec(a0, v0);
            acc_vec(a1, v1);
            i = j;
            if (!more) break;
        }
    }
    if (i < nvec) {
        vf4 v0 = xv[i];
        acc_vec(a0, v0);
    }
    // scalar tail (0..3 elements)
    const int done = pre + (nvec << 2);
    const int rem = C - done;
    if (tid < rem) {
        float v = xr[done + tid];
        float nm = fmaxf(a0.m, v);
        a0.s = a0.s * __expf(a0.m - nm) + __expf(v - nm);
        a0.m = nm;
        a0.sx += v;
    }
    acc_merge(a0, a1.m, a1.s, a1.sx);

    // wave(64) reduce of (m, s, sx)
    for (int off = 32; off > 0; off >>= 1) {
        float mo  = __shfl_down(a0.m,  off, 64);
        float so  = __shfl_down(a0.s,  off, 64);
        float sxo = __shfl_down(a0.sx, off, 64);
        acc_merge(a0, mo, so, sxo);
    }

    __shared__ float sh_m[4], sh_s[4], sh_sx[4];
    const int wave = tid >> 6, lane = tid & 63;
    if (lane == 0) { sh_m[wave] = a0.m; sh_s[wave] = a0.s; sh_sx[wave] = a0.sx; }
    __syncthreads();

    if (tid == 0) {
        Acc A = { sh_m[0], sh_s[0], sh_sx[0] };
        for (int wv = 1; wv < 4; ++wv) acc_merge(A, sh_m[wv], sh_s[wv], sh_sx[wv]);
        ws[row] = make_float4(A.m, A.s, A.sx, 0.0f);
    }
}

// One row per THREAD across 8 blocks (2048-way parallel f64 LambertW chain).
__global__ __launch_bounds__(256) void
mid_kernel(const float4* __restrict__ ws, const float* __restrict__ x,
           const int* __restrict__ tgt, double2* __restrict__ part,
           int B, int C) {
    __shared__ double shA[256], shB[256];
    const int tid = threadIdx.x;
    const int row = blockIdx.x * 256 + tid;
    const double tau = log((double)C);
    const double Econst = 2.718281828459045235360287;

    double sl = 0.0, loss = 0.0;
    if (row < B) {
        float4 r = ws[row];
        const double M = (double)r.x;
        const double lse = log((double)r.y);
        const double SX = (double)r.z;
        const double xt = (double)x[(size_t)row * (size_t)C + tgt[row]];
        const double ce = M + lse - xt;             // -log_softmax[target]
        const double pt = exp(-ce);
        const double omp = 1.0 - pt;
        const double focal = ALPHA * omp * omp * ce;
        const double cl = focal - tau;
        // SuperLoss sigma via principal-branch Lambert W (Halley, 20 iters
        // -- identical op order across revisions for bit-stability)
        double y_ = 0.5 * fmax(-2.0 / Econst, cl / LAM);
        double y  = fmax(y_, -exp(-1.0) + 1e-7);
        double p  = sqrt(2.0 * (Econst * y + 1.0));
        double w  = (y < 0.0) ? (-1.0 + p - p * p / 3.0) : log1p(y);
        for (int it = 0; it < 20; ++it) {
            double ew = exp(w);
            double f  = w * ew - y;
            double w1 = w + 1.0;
            w = w - f / (ew * w1 - (w + 2.0) * f / (2.0 * w1));
        }
        const double sigma = exp(-w);
        const double lw = log(sigma);
        sl   = cl * sigma + LAM * lw * lw;
        loss = (double)C * (M + lse) - SX;          // -sum(log_softmax) of row
    }
    shA[tid] = sl; shB[tid] = loss;
    __syncthreads();
    for (int off = 128; off > 0; off >>= 1) {
        if (tid < off) { shA[tid] += shA[tid + off]; shB[tid] += shB[tid + off]; }
        __syncthreads();
    }
    if (tid == 0) part[blockIdx.x] = make_double2(shA[0], shB[0]);
}

__global__ void
final_kernel(const double2* __restrict__ part, float* __restrict__ out,
             int npart, int B, int C) {
    if (threadIdx.x != 0) return;
    double sl_sum = 0.0, loss_sum = 0.0;
    for (int i = 0; i < npart; ++i) { sl_sum += part[i].x; loss_sum += part[i].y; }
    const double sl_mean = sl_sum / (double)B;
    const double loss    = loss_sum / (double)B;
    const double loss_cls = loss * (EPS_LS / (double)C) + (1.0 - EPS_LS) * sl_mean;
    out[0] = (float)loss_cls;
    out[1] = (float)exp(sl_mean);
}

extern "C" void kernel_launch(void* const* d_in, const int* in_sizes, int n_in,
                              void* d_out, int out_size, void* d_ws, size_t ws_size,
                              hipStream_t stream) {
    const float* x   = (const float*)d_in[0];
    const int*   tgt = (const int*)d_in[1];
    float* out = (float*)d_out;
    float4* ws = (float4*)d_ws;

    const int B = in_sizes[1];
    const int C = in_sizes[0] / B;

    const int nmid = (B + 255) / 256;
    // partials live after the B float4 row records (B*16 bytes, 16B aligned)
    double2* part = reinterpret_cast<double2*>((char*)d_ws + (size_t)B * 16);

    row_kernel<<<B, 256, 0, stream>>>(x, ws, C);
    mid_kernel<<<nmid, 256, 0, stream>>>(ws, x, tgt, part, B, C);
    final_kernel<<<1, 64, 0, stream>>>(part, out, nmid, B, C);
}

// Round 3
// 506.473 us; speedup vs baseline: 1.0715x; 1.0715x over previous
//
#include <hip/hip_runtime.h>
#include <hip/hip_bf16.h>
#include <math.h>

// Fused LabelSmoothingCrossEntropy + Focal + SuperLoss(LambertW) over
// [B=2048, C=50257] fp32 logits. Memory-bound: one pass over 412 MB.
//
// R5: single-lever change off R3 (R4's 3-lever experiment regressed and
// is reverted). Theory: row_kernel is MLP-bound (~1.65 TB/s with only
// 2 KB/wave in flight). This round: 4 independent nontemporal vf4 loads
// per iteration into 4 independent accumulators -> 4 KB/wave in flight,
// load issue fully decoupled from the online-softmax dependency chains.
// Everything else identical to R3 (nt loads, unconditional acc_vec,
// default launch bounds, mid/final kernels untouched).

#define EPS_LS 0.01
#define LAM 0.5
#define ALPHA 0.25

typedef float vf4 __attribute__((ext_vector_type(4)));

struct Acc { float m, s, sx; };

__device__ __forceinline__ void acc_vec(Acc& a, vf4 v) {
    float mx = fmaxf(fmaxf(v.x, v.y), fmaxf(v.z, v.w));
    float nm = fmaxf(a.m, mx);
    a.s = a.s * __expf(a.m - nm)
        + __expf(v.x - nm) + __expf(v.y - nm)
        + __expf(v.z - nm) + __expf(v.w - nm);
    a.m = nm;
    a.sx += (v.x + v.y) + (v.z + v.w);
}

__device__ __forceinline__ void acc_merge(Acc& a, float mo, float so, float sxo) {
    float nm = fmaxf(a.m, mo);
    a.s = a.s * __expf(a.m - nm) + so * __expf(mo - nm);
    a.m = nm;
    a.sx += sxo;
}

__global__ __launch_bounds__(256) void
row_kernel(const float* __restrict__ x, float4* __restrict__ ws, int C) {
    const int row = blockIdx.x;
    const int tid = threadIdx.x;
    const float* xr = x + (size_t)row * (size_t)C;

    Acc a0 = { -3.402823466e38f, 0.0f, 0.0f };
    Acc a1 = { -3.402823466e38f, 0.0f, 0.0f };
    Acc a2 = { -3.402823466e38f, 0.0f, 0.0f };
    Acc a3 = { -3.402823466e38f, 0.0f, 0.0f };

    // peel to 16B alignment (rows start at row*C, C%4==1 -> rotates)
    const int mis = (int)(((size_t)row * (size_t)C) & 3);
    const int pre = (4 - mis) & 3;
    if (tid < pre) {
        float v = xr[tid];
        a0.m = v; a0.s = 1.0f; a0.sx = v;
    }
    const int nvec = (C - pre) >> 2;
    const vf4* xv = reinterpret_cast<const vf4*>(xr + pre);

    // main loop: 4 independent loads (4 KB/wave in flight), 4 independent
    // accumulator chains -- no serial dependency between load and the
    // other three acc chains.
    int i = tid;
    for (; i + 768 < nvec; i += 1024) {
        vf4 v0 = __builtin_nontemporal_load(&xv[i]);
        vf4 v1 = __builtin_nontemporal_load(&xv[i + 256]);
        vf4 v2 = __builtin_nontemporal_load(&xv[i + 512]);
        vf4 v3 = __builtin_nontemporal_load(&xv[i + 768]);
        acc_vec(a0, v0);
        acc_vec(a1, v1);
        acc_vec(a2, v2);
        acc_vec(a3, v3);
    }
    // cleanup stripes (up to 3 full + 1 partial)
    for (; i < nvec; i += 256) {
        vf4 v0 = __builtin_nontemporal_load(&xv[i]);
        acc_vec(a0, v0);
    }
    // scalar tail (0..3 elements)
    const int done = pre + (nvec << 2);
    const int rem = C - done;
    if (tid < rem) {
        float v = xr[done + tid];
        float nm = fmaxf(a0.m, v);
        a0.s = a0.s * __expf(a0.m - nm) + __expf(v - nm);
        a0.m = nm;
        a0.sx += v;
    }
    acc_merge(a0, a1.m, a1.s, a1.sx);
    acc_merge(a2, a3.m, a3.s, a3.sx);
    acc_merge(a0, a2.m, a2.s, a2.sx);

    // wave(64) reduce of (m, s, sx)
    for (int off = 32; off > 0; off >>= 1) {
        float mo  = __shfl_down(a0.m,  off, 64);
        float so  = __shfl_down(a0.s,  off, 64);
        float sxo = __shfl_down(a0.sx, off, 64);
        acc_merge(a0, mo, so, sxo);
    }

    __shared__ float sh_m[4], sh_s[4], sh_sx[4];
    const int wave = tid >> 6, lane = tid & 63;
    if (lane == 0) { sh_m[wave] = a0.m; sh_s[wave] = a0.s; sh_sx[wave] = a0.sx; }
    __syncthreads();

    if (tid == 0) {
        Acc A = { sh_m[0], sh_s[0], sh_sx[0] };
        for (int wv = 1; wv < 4; ++wv) acc_merge(A, sh_m[wv], sh_s[wv], sh_sx[wv]);
        ws[row] = make_float4(A.m, A.s, A.sx, 0.0f);
    }
}

// One row per THREAD across 8 blocks (2048-way parallel f64 LambertW chain).
__global__ __launch_bounds__(256) void
mid_kernel(const float4* __restrict__ ws, const float* __restrict__ x,
           const int* __restrict__ tgt, double2* __restrict__ part,
           int B, int C) {
    __shared__ double shA[256], shB[256];
    const int tid = threadIdx.x;
    const int row = blockIdx.x * 256 + tid;
    const double tau = log((double)C);
    const double Econst = 2.718281828459045235360287;

    double sl = 0.0, loss = 0.0;
    if (row < B) {
        float4 r = ws[row];
        const double M = (double)r.x;
        const double lse = log((double)r.y);
        const double SX = (double)r.z;
        const double xt = (double)x[(size_t)row * (size_t)C + tgt[row]];
        const double ce = M + lse - xt;             // -log_softmax[target]
        const double pt = exp(-ce);
        const double omp = 1.0 - pt;
        const double focal = ALPHA * omp * omp * ce;
        const double cl = focal - tau;
        // SuperLoss sigma via principal-branch Lambert W (Halley, 20 iters
        // -- identical op order across revisions for bit-stability)
        double y_ = 0.5 * fmax(-2.0 / Econst, cl / LAM);
        double y  = fmax(y_, -exp(-1.0) + 1e-7);
        double p  = sqrt(2.0 * (Econst * y + 1.0));
        double w  = (y < 0.0) ? (-1.0 + p - p * p / 3.0) : log1p(y);
        for (int it = 0; it < 20; ++it) {
            double ew = exp(w);
            double f  = w * ew - y;
            double w1 = w + 1.0;
            w = w - f / (ew * w1 - (w + 2.0) * f / (2.0 * w1));
        }
        const double sigma = exp(-w);
        const double lw = log(sigma);
        sl   = cl * sigma + LAM * lw * lw;
        loss = (double)C * (M + lse) - SX;          // -sum(log_softmax) of row
    }
    shA[tid] = sl; shB[tid] = loss;
    __syncthreads();
    for (int off = 128; off > 0; off >>= 1) {
        if (tid < off) { shA[tid] += shA[tid + off]; shB[tid] += shB[tid + off]; }
        __syncthreads();
    }
    if (tid == 0) part[blockIdx.x] = make_double2(shA[0], shB[0]);
}

__global__ void
final_kernel(const double2* __restrict__ part, float* __restrict__ out,
             int npart, int B, int C) {
    if (threadIdx.x != 0) return;
    double sl_sum = 0.0, loss_sum = 0.0;
    for (int i = 0; i < npart; ++i) { sl_sum += part[i].x; loss_sum += part[i].y; }
    const double sl_mean = sl_sum / (double)B;
    const double loss    = loss_sum / (double)B;
    const double loss_cls = loss * (EPS_LS / (double)C) + (1.0 - EPS_LS) * sl_mean;
    out[0] = (float)loss_cls;
    out[1] = (float)exp(sl_mean);
}

extern "C" void kernel_launch(void* const* d_in, const int* in_sizes, int n_in,
                              void* d_out, int out_size, void* d_ws, size_t ws_size,
                              hipStream_t stream) {
    const float* x   = (const float*)d_in[0];
    const int*   tgt = (const int*)d_in[1];
    float* out = (float*)d_out;
    float4* ws = (float4*)d_ws;

    const int B = in_sizes[1];
    const int C = in_sizes[0] / B;

    const int nmid = (B + 255) / 256;
    // partials live after the B float4 row records (B*16 bytes, 16B aligned)
    double2* part = reinterpret_cast<double2*>((char*)d_ws + (size_t)B * 16);

    row_kernel<<<B, 256, 0, stream>>>(x, ws, C);
    mid_kernel<<<nmid, 256, 0, stream>>>(ws, x, tgt, part, B, C);
    final_kernel<<<1, 64, 0, stream>>>(part, out, nmid, B, C);
}